// Round 4
// baseline (2116.073 us; speedup 1.0000x reference)
//
#include <hip/hip_runtime.h>

// CfC fused scan, round 4: 16-wave blocks (1024 thr) to get 4 waves/SIMD.
// 16 blocks x 16 batch rows. Weight payload split across 16 waves:
//   cls0 (wv<8):  Wb kk0..4 of col-tile w8 (incl x part)   20 regs
//   cls1 (wv>=8): Wb kk5..9 of col-tile w8                 20 regs
//   all:          W1/W2/Wat col-tile wv, kk0..3            48 regs
// GEMM_h and p1 are K-split across cls0/cls1 with fp32 partial exchange in
// LDS. Wp1/Wp2 fragment-packed in LDS. Projection pipelined one step behind.
// 3 barriers/step: A1(partials) | A2(z + silu) | B(GEMM_f + blend + p2).

#define T_   512
#define IND  64
#define LAT  256
#define BBD  128
#define OUTD 64
#define HLF  128

typedef _Float16 half8 __attribute__((ext_vector_type(8)));
typedef float    f32x4 __attribute__((ext_vector_type(4)));
typedef float    f4    __attribute__((ext_vector_type(4)));

#define MFMA16(a,b,c) __builtin_amdgcn_mfma_f32_16x16x32_f16((a),(b),(c),0,0,0)

__device__ __forceinline__ float ex2(float x)   { return __builtin_amdgcn_exp2f(x); }
__device__ __forceinline__ float rcpf_(float x) { return __builtin_amdgcn_rcpf(x); }

__global__ void __launch_bounds__(1024, 4) cfc_fused16(
    const float* __restrict__ x,
    const float* __restrict__ Wb,  const float* __restrict__ bb,
    const float* __restrict__ W1,  const float* __restrict__ b1,
    const float* __restrict__ W2,  const float* __restrict__ b2,
    const float* __restrict__ Wa,  const float* __restrict__ ba,
    const float* __restrict__ Wtb, const float* __restrict__ btb,
    const float* __restrict__ Wp1, const float* __restrict__ bp1,
    const float* __restrict__ Wp2, const float* __restrict__ bp2,
    float* __restrict__ out)
{
    const int tid  = threadIdx.x;
    const int wv   = tid >> 6;      // 0..15
    const int cls  = wv >> 3;       // 0 or 1
    const int w8   = wv & 7;        // tile index within class
    const int lane = tid & 63;
    const int l15  = lane & 15;
    const int lg   = lane >> 4;     // 0..3
    const int krow = lg << 3;
    const int b0   = blockIdx.x << 4;

    __shared__ __align__(16) _Float16 wp1l[64*512];   // Wp1 frags 64KB
    __shared__ __align__(16) _Float16 wp2l[16*512];   // Wp2 frags 16KB
    __shared__ __align__(16) _Float16 hbuf[16*LAT];   // h_t        8KB
    __shared__ __align__(16) _Float16 zbuf[16*BBD];   // z_t        4KB
    __shared__ __align__(16) _Float16 dbuf[16*HLF];   // hdn_{t-1}  4KB
    __shared__ __align__(16) float    azp[8*64*4];    // az partials 8KB (cls1)
    __shared__ __align__(16) float    app[8*64*4];    // ap partials 8KB (cls0)

    // ---------------- register weight fragments ----------------------------
    half8 WbB[5];   // gemm-kk = cls*5 + j, col-tile w8
    {
        const int col = (w8 << 4) + l15;
        #pragma unroll
        for (int j = 0; j < 5; ++j) {
            half8 v;
            #pragma unroll
            for (int e = 0; e < 8; ++e)
                v[e] = (_Float16)Wb[((cls*5 + j)*32 + krow + e)*BBD + col];
            WbB[j] = v;
        }
    }
    half8 WfB[3][4];   // W1/W2/Wa+Wtb col-tile wv, 1.7159 folded in
    {
        const int col = (wv << 4) + l15;
        #pragma unroll
        for (int m = 0; m < 3; ++m) {
            const float* Wm = (m==0) ? W1 : ((m==1) ? W2 : Wa);
            #pragma unroll
            for (int kk = 0; kk < 4; ++kk) {
                half8 v;
                #pragma unroll
                for (int e = 0; e < 8; ++e) {
                    const int k = kk*32 + krow + e;
                    float f = Wm[k*LAT + col];
                    if (m == 2) f += Wtb[k*LAT + col];
                    v[e] = (_Float16)(1.7159f * f);
                }
                WfB[m][kk] = v;
            }
        }
    }

    // ---------------- LDS fragment packing (one-time) -----------------------
    {
        #pragma unroll
        for (int f = 0; f < 4; ++f) {           // Wp1: frag g = tt*8+kk
            const int g = (wv << 2) + f, tt = g >> 3, kk = g & 7;
            half8 v;
            #pragma unroll
            for (int e = 0; e < 8; ++e)
                v[e] = (_Float16)Wp1[(kk*32 + krow + e)*HLF + (tt<<4) + l15];
            *(half8*)&wp1l[g*512 + (lane<<3)] = v;
        }
        {                                        // Wp2: frag g = tt*4+kk = wv
            const int tt = wv >> 2, kk = wv & 3;
            half8 v;
            #pragma unroll
            for (int e = 0; e < 8; ++e)
                v[e] = (_Float16)Wp2[(kk*32 + krow + e)*OUTD + (tt<<4) + l15];
            *(half8*)&wp2l[wv*512 + (lane<<3)] = v;
        }
    }
    ((unsigned long long*)hbuf)[tid] = 0ull;    // h0 = 0 (8KB by 1024 thr)

    // ---------------- per-lane bias constants -------------------------------
    const float K1 = 1.4426950408889634f;
    const float K2 = 2.8853900817779268f;
    const float KZ = 1.9216698144680396f;
    const int   cf = (wv << 4) + l15;           // blend col (0..255)
    const int   cs = (w8 << 4) + l15;           // z / silu col (0..127)
    const float b1r  = b1[cf]*K2;
    const float b2r  = b2[cf]*K2;
    const float batr = (ba[cf]+btb[cf])*K1;
    const float bbr  = bb[cs]*KZ;
    const float bp1a = bp1[cs];
    const float bp1k = bp1a*K1;
    const float bp2r = (wv < 4) ? bp2[(wv<<4) + l15] : 0.f;

    const float* xrow = x + (size_t)(b0 + l15) * (T_*IND);
    f4 xq[4];
    if (cls == 0) {
        #pragma unroll
        for (int q = 0; q < 4; ++q)
            xq[q] = *(const f4*)(xrow + ((q>>1)*32 + krow + (q&1)*4));
    }

    const f32x4 fz = {0.f, 0.f, 0.f, 0.f};
    float* const obase = out + (size_t)(b0 + (lg<<2)) * (T_*OUTD) + (wv<<4) + l15;

    __syncthreads();   // hbuf zeros + wp1l/wp2l visible

    #pragma unroll 1
    for (int t = 0; t < T_; ++t) {
        // ========================= PHASE A1 =========================
        half8 ha[5];
        f32x4 az, ap;
        if (cls == 0) {
            #pragma unroll
            for (int j = 0; j < 4; ++j)
                ha[j] = *(const half8*)&hbuf[(l15*LAT + j*32 + krow) ^ ((l15&7)<<3)];
            // x convert + prefetch
            half8 xa0, xa1;
            #pragma unroll
            for (int e = 0; e < 4; ++e) {
                xa0[e]   = (_Float16)xq[0][e];
                xa0[e+4] = (_Float16)xq[1][e];
                xa1[e]   = (_Float16)xq[2][e];
                xa1[e+4] = (_Float16)xq[3][e];
            }
            {
                const int tn = (t < T_-1) ? (t+1) : t;
                const float* p = xrow + tn*IND + krow;
                #pragma unroll
                for (int q = 0; q < 4; ++q)
                    xq[q] = *(const f4*)(p + (q>>1)*32 + (q&1)*4);
            }
            // GEMM_h partial: kk0,1 (x) + kk2..4 (h frags 0..2)
            az = MFMA16(xa0, WbB[0], fz);
            az = MFMA16(xa1, WbB[1], az);
            az = MFMA16(ha[0], WbB[2], az);
            az = MFMA16(ha[1], WbB[3], az);
            az = MFMA16(ha[2], WbB[4], az);
            // p1 partial kk0..3 (h frags 0..3), Wp1 frags from LDS
            ap = fz;
            #pragma unroll
            for (int kk = 0; kk < 4; ++kk)
                ap = MFMA16(ha[kk], *(const half8*)&wp1l[((w8<<3)+kk)*512 + (lane<<3)], ap);
            *(f32x4*)&app[((w8<<6) + lane)<<2] = ap;
        } else {
            #pragma unroll
            for (int j = 0; j < 5; ++j)     // h frags 3..7
                ha[j] = *(const half8*)&hbuf[(l15*LAT + (3+j)*32 + krow) ^ ((l15&7)<<3)];
            // GEMM_h partial: kk5..9 (h frags 3..7)
            az = fz;
            #pragma unroll
            for (int j = 0; j < 5; ++j)
                az = MFMA16(ha[j], WbB[j], az);
            *(f32x4*)&azp[((w8<<6) + lane)<<2] = az;
            // p1 partial kk4..7 (h frags 4..7 = ha[1..4])
            ap = fz;
            #pragma unroll
            for (int kk = 0; kk < 4; ++kk)
                ap = MFMA16(ha[kk+1], *(const half8*)&wp1l[((w8<<3)+4+kk)*512 + (lane<<3)], ap);
        }
        __syncthreads();   // bar1: partials ready

        // ========================= PHASE A2 =========================
        if (cls == 0) {
            az += *(const f32x4*)&azp[((w8<<6) + lane)<<2];
            #pragma unroll
            for (int r = 0; r < 4; ++r) {
                const float E = ex2(__builtin_fmaf(az[r], KZ, bbr));
                const float z = __builtin_fmaf(-2.f, rcpf_(E + 1.f), 1.f);
                const int row = (lg<<2) + r;
                zbuf[(row*BBD + cs) ^ ((row&7)<<3)] = (_Float16)z;
            }
        } else {
            ap += *(const f32x4*)&app[((w8<<6) + lane)<<2];
            #pragma unroll
            for (int r = 0; r < 4; ++r) {
                const float v  = ap[r] + bp1a;
                const float E  = ex2(__builtin_fmaf(ap[r], K1, bp1k));
                const float sg = rcpf_(E + 1.f);
                const float hd = __builtin_fmaf(-v, sg, v);
                const int row = (lg<<2) + r;
                dbuf[(row*HLF + cs) ^ ((row&7)<<3)] = (_Float16)hd;
            }
        }
        __syncthreads();   // bar2: zbuf/dbuf complete

        // ========================= PHASE B ==========================
        half8 za[4];
        #pragma unroll
        for (int kk = 0; kk < 4; ++kk)
            za[kk] = *(const half8*)&zbuf[(l15*BBD + kk*32 + krow) ^ ((l15&7)<<3)];
        f32x4 af0 = fz, af1 = fz, af2 = fz;
        #pragma unroll
        for (int kk = 0; kk < 4; ++kk) {
            af0 = MFMA16(za[kk], WfB[0][kk], af0);
            af1 = MFMA16(za[kk], WfB[1][kk], af1);
            af2 = MFMA16(za[kk], WfB[2][kk], af2);
        }
        #pragma unroll
        for (int r = 0; r < 4; ++r) {
            const float E1 = ex2(__builtin_fmaf(af0[r], K2, b1r));
            const float E2 = ex2(__builtin_fmaf(af1[r], K2, b2r));
            const float E3 = ex2(__builtin_fmaf(af2[r], K1, batr));
            const float p1_ = E1 + 1.f;
            const float p2_ = E2 + 1.f;
            const float p3_ = E3 + 1.f;
            const float num = __builtin_fmaf(E3, p1_, p2_);
            const float hv  = __builtin_fmaf(-2.f*num, rcpf_(p1_*p2_*p3_), 1.f);
            const int row = (lg<<2) + r;
            hbuf[(row*LAT + cf) ^ ((row&7)<<3)] = (_Float16)hv;
        }
        // p2 for t-1 (waves 0..3)
        if (wv < 4) {
            f32x4 ao = fz;
            #pragma unroll
            for (int kk = 0; kk < 4; ++kk) {
                const half8 pa = *(const half8*)&dbuf[(l15*HLF + kk*32 + krow) ^ ((l15&7)<<3)];
                ao = MFMA16(pa, *(const half8*)&wp2l[((wv<<2)+kk)*512 + (lane<<3)], ao);
            }
            if (t > 0) {
                #pragma unroll
                for (int r = 0; r < 4; ++r)
                    obase[(size_t)r*(T_*OUTD) + (size_t)(t-1)*OUTD] = ao[r] + bp2r;
            }
        }
        __syncthreads();   // bar3: hbuf ready; azp/app/zbuf/dbuf reusable
    }

    // ===================== epilogue: project h_{511} =====================
    {
        half8 ha[4];
        f32x4 ap = fz;
        if (cls == 0) {
            #pragma unroll
            for (int j = 0; j < 4; ++j)
                ha[j] = *(const half8*)&hbuf[(l15*LAT + j*32 + krow) ^ ((l15&7)<<3)];
            #pragma unroll
            for (int kk = 0; kk < 4; ++kk)
                ap = MFMA16(ha[kk], *(const half8*)&wp1l[((w8<<3)+kk)*512 + (lane<<3)], ap);
            *(f32x4*)&app[((w8<<6) + lane)<<2] = ap;
        } else {
            #pragma unroll
            for (int j = 0; j < 4; ++j)
                ha[j] = *(const half8*)&hbuf[(l15*LAT + (4+j)*32 + krow) ^ ((l15&7)<<3)];
            #pragma unroll
            for (int kk = 0; kk < 4; ++kk)
                ap = MFMA16(ha[kk], *(const half8*)&wp1l[((w8<<3)+4+kk)*512 + (lane<<3)], ap);
        }
        __syncthreads();
        if (cls == 1) {
            ap += *(const f32x4*)&app[((w8<<6) + lane)<<2];
            #pragma unroll
            for (int r = 0; r < 4; ++r) {
                const float v  = ap[r] + bp1a;
                const float E  = ex2(__builtin_fmaf(ap[r], K1, bp1k));
                const float sg = rcpf_(E + 1.f);
                const float hd = __builtin_fmaf(-v, sg, v);
                const int row = (lg<<2) + r;
                dbuf[(row*HLF + cs) ^ ((row&7)<<3)] = (_Float16)hd;
            }
        }
        __syncthreads();
        if (wv < 4) {
            f32x4 ao = fz;
            #pragma unroll
            for (int kk = 0; kk < 4; ++kk) {
                const half8 pa = *(const half8*)&dbuf[(l15*HLF + kk*32 + krow) ^ ((l15&7)<<3)];
                ao = MFMA16(pa, *(const half8*)&wp2l[((wv<<2)+kk)*512 + (lane<<3)], ao);
            }
            #pragma unroll
            for (int r = 0; r < 4; ++r)
                obase[(size_t)r*(T_*OUTD) + (size_t)(T_-1)*OUTD] = ao[r] + bp2r;
        }
    }
}

extern "C" void kernel_launch(void* const* d_in, const int* in_sizes, int n_in,
                              void* d_out, int out_size, void* d_ws, size_t ws_size,
                              hipStream_t stream) {
    (void)in_sizes; (void)n_in; (void)out_size; (void)d_ws; (void)ws_size;
    const float* x   = (const float*)d_in[0];
    const float* Wb  = (const float*)d_in[1];
    const float* bb  = (const float*)d_in[2];
    const float* W1  = (const float*)d_in[3];
    const float* b1  = (const float*)d_in[4];
    const float* W2  = (const float*)d_in[5];
    const float* b2  = (const float*)d_in[6];
    const float* Wa  = (const float*)d_in[7];
    const float* ba  = (const float*)d_in[8];
    const float* Wtb = (const float*)d_in[9];
    const float* btb = (const float*)d_in[10];
    const float* Wp1 = (const float*)d_in[11];
    const float* bp1 = (const float*)d_in[12];
    const float* Wp2 = (const float*)d_in[13];
    const float* bp2 = (const float*)d_in[14];
    cfc_fused16<<<dim3(16), dim3(1024), 0, stream>>>(
        x, Wb, bb, W1, b1, W2, b2, Wa, ba, Wtb, btb, Wp1, bp1, Wp2, bp2,
        (float*)d_out);
}

// Round 5
// 815.016 us; speedup vs baseline: 2.5964x; 2.5964x over previous
//
#include <hip/hip_runtime.h>

// CfC, round 5: scan/projection split.
//  K1 cfc_scan: 16 blocks x 512 thr (8 waves, 2/SIMD). Recurrence only:
//     phase A: reload ha; GEMM_h ([x|h]@Wb, 3 parallel MFMA chains) -> z
//     phase B: GEMM_f (z@[W1|W2|Wat]) -> blend -> h_t -> hbuf + seq(global fp16)
//     2 barriers/step. Weights register-resident (Wb 40 + Wf 96 frags).
//  K2 cfc_proj: 2048 blocks x 256 thr; out = silu(seq@Wp1+bp1)@Wp2+bp2.
//  Fallback (ws too small): R3 fused kernel.

#define T_   512
#define IND  64
#define LAT  256
#define BBD  128
#define OUTD 64
#define HLF  128

typedef _Float16 half8 __attribute__((ext_vector_type(8)));
typedef float    f32x4 __attribute__((ext_vector_type(4)));
typedef float    f4    __attribute__((ext_vector_type(4)));

#define MFMA16(a,b,c) __builtin_amdgcn_mfma_f32_16x16x32_f16((a),(b),(c),0,0,0)

__device__ __forceinline__ float ex2(float x)   { return __builtin_amdgcn_exp2f(x); }
__device__ __forceinline__ float rcpf_(float x) { return __builtin_amdgcn_rcpf(x); }

// ============================ K1: recurrence scan ============================
__global__ void __launch_bounds__(512, 2) cfc_scan(
    const float* __restrict__ x,
    const float* __restrict__ Wb,  const float* __restrict__ bb,
    const float* __restrict__ W1,  const float* __restrict__ b1,
    const float* __restrict__ W2,  const float* __restrict__ b2,
    const float* __restrict__ Wa,  const float* __restrict__ ba,
    const float* __restrict__ Wtb, const float* __restrict__ btb,
    _Float16* __restrict__ seq)
{
    const int tid  = threadIdx.x;
    const int wv   = tid >> 6;
    const int lane = tid & 63;
    const int l15  = lane & 15;
    const int lg   = lane >> 4;
    const int krow = lg << 3;
    const int b0   = blockIdx.x << 4;

    __shared__ __align__(16) _Float16 hbuf[16*LAT];   // 8KB
    __shared__ __align__(16) _Float16 zbuf[16*BBD];   // 4KB

    half8 WbB[10];
    {
        const int col = (wv<<4) + l15;
        #pragma unroll
        for (int kk = 0; kk < 10; ++kk) {
            half8 v;
            #pragma unroll
            for (int e = 0; e < 8; ++e)
                v[e] = (_Float16)Wb[(kk*32 + krow + e)*BBD + col];
            WbB[kk] = v;
        }
    }
    half8 WfB[6][4];   // 0,1=W1 2,3=W2 4,5=Wa+Wtb ; 1.7159 folded
    #pragma unroll
    for (int t6 = 0; t6 < 6; ++t6) {
        const int m   = t6 >> 1;
        const int col = (wv<<5) + ((t6&1)<<4) + l15;
        const float* Wm = (m==0) ? W1 : ((m==1) ? W2 : Wa);
        #pragma unroll
        for (int kk = 0; kk < 4; ++kk) {
            half8 v;
            #pragma unroll
            for (int e = 0; e < 8; ++e) {
                const int k = kk*32 + krow + e;
                float f = Wm[k*LAT + col];
                if (m == 2) f += Wtb[k*LAT + col];
                v[e] = (_Float16)(1.7159f * f);
            }
            WfB[t6][kk] = v;
        }
    }

    const float K1 = 1.4426950408889634f;
    const float K2 = 2.8853900817779268f;
    const float KZ = 1.9216698144680396f;
    const int cz  = (wv<<4) + l15;
    const int cf0 = (wv<<5) + l15;
    const int cf1 = cf0 + 16;
    const float bbr   = bb[cz] * KZ;
    const float b1r0  = b1[cf0]*K2,  b1r1  = b1[cf1]*K2;
    const float b2r0  = b2[cf0]*K2,  b2r1  = b2[cf1]*K2;
    const float batr0 = (ba[cf0]+btb[cf0])*K1, batr1 = (ba[cf1]+btb[cf1])*K1;

    const float* xrow = x + (size_t)(b0 + l15) * (T_*IND);
    f4 xq[4];
    #pragma unroll
    for (int q = 0; q < 4; ++q)
        xq[q] = *(const f4*)(xrow + ((q>>1)*32 + krow + (q&1)*4));

    half8 ha[8];
    {
        half8 hz;
        #pragma unroll
        for (int e = 0; e < 8; ++e) hz[e] = (_Float16)0.f;
        #pragma unroll
        for (int i = 0; i < 8; ++i) ha[i] = hz;
    }
    const f32x4 fz = {0.f, 0.f, 0.f, 0.f};
    // seq row-base for this thread's 4 output rows (r adds r*T_*LAT)
    _Float16* const sbase = seq + (size_t)(b0 + (lg<<2)) * (T_*LAT) + (wv<<5) + l15;

    #pragma unroll 1
    for (int t = 0; t < T_; ++t) {
        // ---------------- phase A ----------------
        if (t > 0) {
            #pragma unroll
            for (int kk = 0; kk < 8; ++kk)
                ha[kk] = *(const half8*)&hbuf[(l15*LAT + kk*32 + krow) ^ ((l15&7)<<3)];
        }
        half8 xa0, xa1;
        #pragma unroll
        for (int e = 0; e < 4; ++e) {
            xa0[e]   = (_Float16)xq[0][e];
            xa0[e+4] = (_Float16)xq[1][e];
            xa1[e]   = (_Float16)xq[2][e];
            xa1[e+4] = (_Float16)xq[3][e];
        }
        {
            const int tn = (t < T_-1) ? (t+1) : t;
            const float* p = xrow + tn*IND + krow;
            #pragma unroll
            for (int q = 0; q < 4; ++q)
                xq[q] = *(const f4*)(p + (q>>1)*32 + (q&1)*4);
        }
        // GEMM_h: 3 parallel chains (depth 2,4,4) + tree sum
        f32x4 azx = MFMA16(xa0, WbB[0], fz);
        azx = MFMA16(xa1, WbB[1], azx);
        f32x4 az0 = MFMA16(ha[0], WbB[2], fz);
        f32x4 az1 = MFMA16(ha[1], WbB[3], fz);
        #pragma unroll
        for (int kk = 2; kk < 8; kk += 2) {
            az0 = MFMA16(ha[kk],   WbB[kk+2], az0);
            az1 = MFMA16(ha[kk+1], WbB[kk+3], az1);
        }
        const f32x4 az = (azx + az0) + az1;

        #pragma unroll
        for (int r = 0; r < 4; ++r) {
            const float E = ex2(__builtin_fmaf(az[r], KZ, bbr));
            const float z = __builtin_fmaf(-2.f, rcpf_(E + 1.f), 1.f);
            const int row = (lg<<2) + r;
            zbuf[(row*BBD + cz) ^ ((row&7)<<3)] = (_Float16)z;
        }
        __syncthreads();   // zbuf ready

        // ---------------- phase B ----------------
        half8 za[4];
        #pragma unroll
        for (int kk = 0; kk < 4; ++kk)
            za[kk] = *(const half8*)&zbuf[(l15*BBD + kk*32 + krow) ^ ((l15&7)<<3)];
        f32x4 af[6];
        #pragma unroll
        for (int i = 0; i < 6; ++i) af[i] = fz;
        #pragma unroll
        for (int kk = 0; kk < 4; ++kk) {
            #pragma unroll
            for (int i = 0; i < 6; ++i) af[i] = MFMA16(za[kk], WfB[i][kk], af[i]);
        }
        _Float16* const sp = sbase + (size_t)t * LAT;
        #pragma unroll
        for (int sub = 0; sub < 2; ++sub) {
            const float b1r  = sub ? b1r1  : b1r0;
            const float b2r  = sub ? b2r1  : b2r0;
            const float batr = sub ? batr1 : batr0;
            #pragma unroll
            for (int r = 0; r < 4; ++r) {
                const float E1 = ex2(__builtin_fmaf(af[0+sub][r], K2, b1r));
                const float E2 = ex2(__builtin_fmaf(af[2+sub][r], K2, b2r));
                const float E3 = ex2(__builtin_fmaf(af[4+sub][r], K1, batr));
                const float p1_ = E1 + 1.f;
                const float p2_ = E2 + 1.f;
                const float p3_ = E3 + 1.f;
                const float num = __builtin_fmaf(E3, p1_, p2_);
                const float hv  = __builtin_fmaf(-2.f*num, rcpf_(p1_*p2_*p3_), 1.f);
                const _Float16 hh = (_Float16)hv;
                const int row = (lg<<2) + r;
                hbuf[(row*LAT + (wv<<5) + (sub<<4) + l15) ^ ((row&7)<<3)] = hh;
                sp[(size_t)r*(T_*LAT) + (sub<<4)] = hh;
            }
        }
        __syncthreads();   // hbuf ready for t+1
    }
}

// ============================ K2: projection =================================
__global__ void __launch_bounds__(256, 2) cfc_proj(
    const _Float16* __restrict__ seq,
    const float* __restrict__ Wp1, const float* __restrict__ bp1,
    const float* __restrict__ Wp2, const float* __restrict__ bp2,
    float* __restrict__ out)
{
    const int tid  = threadIdx.x;
    const int wv   = tid >> 6;      // 0..3
    const int lane = tid & 63;
    const int l15  = lane & 15;
    const int lg   = lane >> 4;
    const int krow = lg << 3;

    __shared__ __align__(16) _Float16 wp1l[64*512];      // 64KB
    __shared__ __align__(16) _Float16 wp2l[16*512];      // 16KB
    __shared__ __align__(16) _Float16 dbuf[4][16*HLF];   // 16KB

    // pack Wp1 (64 frags: g = tt*8 + kk) and Wp2 (16 frags: g = tt*4 + kk)
    #pragma unroll
    for (int f = 0; f < 16; ++f) {
        const int g = wv*16 + f, tt = g >> 3, kk = g & 7;
        half8 v;
        #pragma unroll
        for (int e = 0; e < 8; ++e)
            v[e] = (_Float16)Wp1[(kk*32 + krow + e)*HLF + (tt<<4) + l15];
        *(half8*)&wp1l[g*512 + (lane<<3)] = v;
    }
    #pragma unroll
    for (int f = 0; f < 4; ++f) {
        const int g = wv*4 + f, tt = g >> 2, kk = g & 3;
        half8 v;
        #pragma unroll
        for (int e = 0; e < 8; ++e)
            v[e] = (_Float16)Wp2[(kk*32 + krow + e)*OUTD + (tt<<4) + l15];
        *(half8*)&wp2l[g*512 + (lane<<3)] = v;
    }

    const float K1 = 1.4426950408889634f;
    float bp1v[8], bp1kv[8];
    #pragma unroll
    for (int tt = 0; tt < 8; ++tt) {
        bp1v[tt]  = bp1[(tt<<4) + l15];
        bp1kv[tt] = bp1v[tt] * K1;
    }
    float bp2v[4];
    #pragma unroll
    for (int tt = 0; tt < 4; ++tt) bp2v[tt] = bp2[(tt<<4) + l15];

    __syncthreads();

    const int m0 = (blockIdx.x*4 + wv) << 4;   // 16-row tile base
    const f32x4 fz = {0.f, 0.f, 0.f, 0.f};

    // A-frags of seq (global, contiguous 16B)
    half8 ha[8];
    {
        const _Float16* ap = seq + (size_t)(m0 + l15)*LAT + krow;
        #pragma unroll
        for (int kk = 0; kk < 8; ++kk)
            ha[kk] = *(const half8*)(ap + kk*32);
    }

    // p1 + silu -> dbuf (per-wave slice; wave-internal LDS ordering suffices)
    #pragma unroll
    for (int tt = 0; tt < 8; ++tt) {
        f32x4 a0 = fz, a1 = fz;
        #pragma unroll
        for (int kk = 0; kk < 8; kk += 2) {
            a0 = MFMA16(ha[kk],   *(const half8*)&wp1l[((tt<<3)+kk  )*512 + (lane<<3)], a0);
            a1 = MFMA16(ha[kk+1], *(const half8*)&wp1l[((tt<<3)+kk+1)*512 + (lane<<3)], a1);
        }
        const f32x4 ap = a0 + a1;
        #pragma unroll
        for (int r = 0; r < 4; ++r) {
            const float v  = ap[r] + bp1v[tt];
            const float E  = ex2(__builtin_fmaf(ap[r], K1, bp1kv[tt]));
            const float sg = rcpf_(E + 1.f);
            const float hd = __builtin_fmaf(-v, sg, v);
            const int row = (lg<<2) + r;
            dbuf[wv][(row*HLF + (tt<<4) + l15) ^ ((row&7)<<3)] = (_Float16)hd;
        }
    }

    // p2
    half8 pa[4];
    #pragma unroll
    for (int kk = 0; kk < 4; ++kk)
        pa[kk] = *(const half8*)&dbuf[wv][(l15*HLF + kk*32 + krow) ^ ((l15&7)<<3)];
    #pragma unroll
    for (int tt = 0; tt < 4; ++tt) {
        f32x4 ao = fz;
        #pragma unroll
        for (int kk = 0; kk < 4; ++kk)
            ao = MFMA16(pa[kk], *(const half8*)&wp2l[((tt<<2)+kk)*512 + (lane<<3)], ao);
        #pragma unroll
        for (int r = 0; r < 4; ++r)
            out[(size_t)(m0 + (lg<<2) + r)*OUTD + (tt<<4) + l15] = ao[r] + bp2v[tt];
    }
}

// ==================== fallback: R3 fused kernel (ws too small) ===============
__global__ void __launch_bounds__(512, 2) cfc_fused_fb(
    const float* __restrict__ x,
    const float* __restrict__ Wb,  const float* __restrict__ bb,
    const float* __restrict__ W1,  const float* __restrict__ b1,
    const float* __restrict__ W2,  const float* __restrict__ b2,
    const float* __restrict__ Wa,  const float* __restrict__ ba,
    const float* __restrict__ Wtb, const float* __restrict__ btb,
    const float* __restrict__ Wp1, const float* __restrict__ bp1,
    const float* __restrict__ Wp2, const float* __restrict__ bp2,
    float* __restrict__ out)
{
    const int tid  = threadIdx.x;
    const int wv   = tid >> 6;
    const int lane = tid & 63;
    const int l15  = lane & 15;
    const int lg   = lane >> 4;
    const int krow = lg << 3;
    const int b0   = blockIdx.x << 4;

    __shared__ __align__(16) _Float16 hbuf[16*LAT];
    __shared__ __align__(16) _Float16 zbuf[16*BBD];
    __shared__ __align__(16) _Float16 dbuf[16*HLF];
    __shared__ __align__(16) _Float16 wp1l[64*512];
    __shared__ __align__(16) _Float16 wp2l[16*512];

    half8 WbB[10];
    {
        const int col = (wv<<4) + l15;
        #pragma unroll
        for (int kk = 0; kk < 10; ++kk) {
            half8 v;
            #pragma unroll
            for (int e = 0; e < 8; ++e)
                v[e] = (_Float16)Wb[(kk*32 + krow + e)*BBD + col];
            WbB[kk] = v;
        }
    }
    half8 WfB[6][4];
    #pragma unroll
    for (int t6 = 0; t6 < 6; ++t6) {
        const int m   = t6 >> 1;
        const int col = (wv<<5) + ((t6&1)<<4) + l15;
        const float* Wm = (m==0) ? W1 : ((m==1) ? W2 : Wa);
        #pragma unroll
        for (int kk = 0; kk < 4; ++kk) {
            half8 v;
            #pragma unroll
            for (int e = 0; e < 8; ++e) {
                const int k = kk*32 + krow + e;
                float f = Wm[k*LAT + col];
                if (m == 2) f += Wtb[k*LAT + col];
                v[e] = (_Float16)(1.7159f * f);
            }
            WfB[t6][kk] = v;
        }
    }
    {
        const int col = (wv<<4) + l15;
        #pragma unroll
        for (int kk = 0; kk < 8; ++kk) {
            half8 v;
            #pragma unroll
            for (int e = 0; e < 8; ++e)
                v[e] = (_Float16)Wp1[(kk*32 + krow + e)*HLF + col];
            *(half8*)&wp1l[((wv<<3) + kk)*512 + (lane<<3)] = v;
        }
        if (wv < 4) {
            #pragma unroll
            for (int kk = 0; kk < 4; ++kk) {
                half8 v;
                #pragma unroll
                for (int e = 0; e < 8; ++e)
                    v[e] = (_Float16)Wp2[(kk*32 + krow + e)*OUTD + col];
                *(half8*)&wp2l[((wv<<2) + kk)*512 + (lane<<3)] = v;
            }
        }
    }
    const _Float16* const wp1p = &wp1l[(wv<<3)*512 + (lane<<3)];
    const _Float16* const wp2p = &wp2l[(wv<<2)*512 + (lane<<3)];

    const float K1 = 1.4426950408889634f;
    const float K2 = 2.8853900817779268f;
    const float KZ = 1.9216698144680396f;
    const int cz  = (wv<<4) + l15;
    const int cf0 = (wv<<5) + l15;
    const int cf1 = cf0 + 16;
    const float bbr   = bb[cz] * KZ;
    const float b1r0  = b1[cf0]*K2,  b1r1  = b1[cf1]*K2;
    const float b2r0  = b2[cf0]*K2,  b2r1  = b2[cf1]*K2;
    const float batr0 = (ba[cf0]+btb[cf0])*K1, batr1 = (ba[cf1]+btb[cf1])*K1;
    const float bp1a  = bp1[cz];
    const float bp1k  = bp1a * K1;
    const float bp2r  = (wv < 4) ? bp2[cz] : 0.f;

    __syncthreads();

    const float* xrow = x + (size_t)(b0 + l15) * (T_*IND);
    f4 xq[4];
    #pragma unroll
    for (int q = 0; q < 4; ++q)
        xq[q] = *(const f4*)(xrow + ((q>>1)*32 + krow + (q&1)*4));

    half8 ha[8];
    {
        half8 hz;
        #pragma unroll
        for (int e = 0; e < 8; ++e) hz[e] = (_Float16)0.f;
        #pragma unroll
        for (int i = 0; i < 8; ++i) ha[i] = hz;
    }
    const f32x4 fz = {0.f, 0.f, 0.f, 0.f};
    float* const obase = out + (size_t)(b0 + (lg<<2)) * (T_*OUTD) + (wv<<4) + l15;

    #pragma unroll 1
    for (int t = 0; t < T_; ++t) {
        if (t > 0) {
            #pragma unroll
            for (int kk = 0; kk < 8; ++kk)
                ha[kk] = *(const half8*)&hbuf[(l15*LAT + kk*32 + krow) ^ ((l15&7)<<3)];
        }
        half8 xa0, xa1;
        #pragma unroll
        for (int e = 0; e < 4; ++e) {
            xa0[e]   = (_Float16)xq[0][e];
            xa0[e+4] = (_Float16)xq[1][e];
            xa1[e]   = (_Float16)xq[2][e];
            xa1[e+4] = (_Float16)xq[3][e];
        }
        {
            const int tn = (t < T_-1) ? (t+1) : t;
            const float* p = xrow + tn*IND + krow;
            #pragma unroll
            for (int q = 0; q < 4; ++q)
                xq[q] = *(const f4*)(p + (q>>1)*32 + (q&1)*4);
        }
        f32x4 az0 = MFMA16(xa0, WbB[0], fz);
        f32x4 az1 = MFMA16(xa1, WbB[1], fz);
        #pragma unroll
        for (int kk = 0; kk < 8; kk += 2) {
            az0 = MFMA16(ha[kk],   WbB[kk+2], az0);
            az1 = MFMA16(ha[kk+1], WbB[kk+3], az1);
        }
        const f32x4 az = az0 + az1;
        #pragma unroll
        for (int r = 0; r < 4; ++r) {
            const float E = ex2(__builtin_fmaf(az[r], KZ, bbr));
            const float z = __builtin_fmaf(-2.f, rcpf_(E + 1.f), 1.f);
            const int row = (lg<<2) + r;
            zbuf[(row*BBD + cz) ^ ((row&7)<<3)] = (_Float16)z;
        }
        if (t > 0) {
            f32x4 ap0 = fz, ap1 = fz;
            #pragma unroll
            for (int kk = 0; kk < 8; kk += 2) {
                ap0 = MFMA16(ha[kk],   *(const half8*)(wp1p +  kk   *512), ap0);
                ap1 = MFMA16(ha[kk+1], *(const half8*)(wp1p + (kk+1)*512), ap1);
            }
            const f32x4 ap = ap0 + ap1;
            #pragma unroll
            for (int r = 0; r < 4; ++r) {
                const float v  = ap[r] + bp1a;
                const float E  = ex2(__builtin_fmaf(ap[r], K1, bp1k));
                const float sg = rcpf_(E + 1.f);
                const float hd = __builtin_fmaf(-v, sg, v);
                const int row = (lg<<2) + r;
                dbuf[(row*HLF + cz) ^ ((row&7)<<3)] = (_Float16)hd;
            }
        }
        __syncthreads();

        half8 za[4];
        #pragma unroll
        for (int kk = 0; kk < 4; ++kk)
            za[kk] = *(const half8*)&zbuf[(l15*BBD + kk*32 + krow) ^ ((l15&7)<<3)];
        f32x4 af[6];
        #pragma unroll
        for (int i = 0; i < 6; ++i) af[i] = fz;
        #pragma unroll
        for (int kk = 0; kk < 4; ++kk) {
            #pragma unroll
            for (int i = 0; i < 6; ++i) af[i] = MFMA16(za[kk], WfB[i][kk], af[i]);
        }
        #pragma unroll
        for (int sub = 0; sub < 2; ++sub) {
            const float b1r  = sub ? b1r1  : b1r0;
            const float b2r  = sub ? b2r1  : b2r0;
            const float batr = sub ? batr1 : batr0;
            #pragma unroll
            for (int r = 0; r < 4; ++r) {
                const float E1 = ex2(__builtin_fmaf(af[0+sub][r], K2, b1r));
                const float E2 = ex2(__builtin_fmaf(af[2+sub][r], K2, b2r));
                const float E3 = ex2(__builtin_fmaf(af[4+sub][r], K1, batr));
                const float p1_ = E1 + 1.f;
                const float p2_ = E2 + 1.f;
                const float p3_ = E3 + 1.f;
                const float num = __builtin_fmaf(E3, p1_, p2_);
                const float hv  = __builtin_fmaf(-2.f*num, rcpf_(p1_*p2_*p3_), 1.f);
                const int row = (lg<<2) + r;
                hbuf[(row*LAT + (wv<<5) + (sub<<4) + l15) ^ ((row&7)<<3)] = (_Float16)hv;
            }
        }
        if (t > 0 && wv < 4) {
            f32x4 ao = fz;
            #pragma unroll
            for (int kk = 0; kk < 4; ++kk) {
                const half8 aa = *(const half8*)&dbuf[(l15*HLF + kk*32 + krow) ^ ((l15&7)<<3)];
                ao = MFMA16(aa, *(const half8*)(wp2p + kk*512), ao);
            }
            #pragma unroll
            for (int r = 0; r < 4; ++r)
                obase[(size_t)r*(T_*OUTD) + (size_t)(t-1)*OUTD] = ao[r] + bp2r;
        }
        __syncthreads();
    }
    {
        #pragma unroll
        for (int kk = 0; kk < 8; ++kk)
            ha[kk] = *(const half8*)&hbuf[(l15*LAT + kk*32 + krow) ^ ((l15&7)<<3)];
        f32x4 ap0 = fz, ap1 = fz;
        #pragma unroll
        for (int kk = 0; kk < 8; kk += 2) {
            ap0 = MFMA16(ha[kk],   *(const half8*)(wp1p +  kk   *512), ap0);
            ap1 = MFMA16(ha[kk+1], *(const half8*)(wp1p + (kk+1)*512), ap1);
        }
        const f32x4 ap = ap0 + ap1;
        #pragma unroll
        for (int r = 0; r < 4; ++r) {
            const float v  = ap[r] + bp1a;
            const float E  = ex2(__builtin_fmaf(ap[r], K1, bp1k));
            const float sg = rcpf_(E + 1.f);
            const float hd = __builtin_fmaf(-v, sg, v);
            const int row = (lg<<2) + r;
            dbuf[(row*HLF + cz) ^ ((row&7)<<3)] = (_Float16)hd;
        }
        __syncthreads();
        if (wv < 4) {
            f32x4 ao = fz;
            #pragma unroll
            for (int kk = 0; kk < 4; ++kk) {
                const half8 aa = *(const half8*)&dbuf[(l15*HLF + kk*32 + krow) ^ ((l15&7)<<3)];
                ao = MFMA16(aa, *(const half8*)(wp2p + kk*512), ao);
            }
            #pragma unroll
            for (int r = 0; r < 4; ++r)
                obase[(size_t)r*(T_*OUTD) + (size_t)(T_-1)*OUTD] = ao[r] + bp2r;
        }
    }
}

extern "C" void kernel_launch(void* const* d_in, const int* in_sizes, int n_in,
                              void* d_out, int out_size, void* d_ws, size_t ws_size,
                              hipStream_t stream) {
    (void)in_sizes; (void)n_in; (void)out_size;
    const float* x   = (const float*)d_in[0];
    const float* Wb  = (const float*)d_in[1];
    const float* bb  = (const float*)d_in[2];
    const float* W1  = (const float*)d_in[3];
    const float* b1  = (const float*)d_in[4];
    const float* W2  = (const float*)d_in[5];
    const float* b2  = (const float*)d_in[6];
    const float* Wa  = (const float*)d_in[7];
    const float* ba  = (const float*)d_in[8];
    const float* Wtb = (const float*)d_in[9];
    const float* btb = (const float*)d_in[10];
    const float* Wp1 = (const float*)d_in[11];
    const float* bp1 = (const float*)d_in[12];
    const float* Wp2 = (const float*)d_in[13];
    const float* bp2 = (const float*)d_in[14];

    const size_t seq_bytes = (size_t)256 * T_ * LAT * sizeof(_Float16); // 67MB
    if (ws_size >= seq_bytes) {
        _Float16* seq = (_Float16*)d_ws;
        cfc_scan<<<dim3(16), dim3(512), 0, stream>>>(
            x, Wb, bb, W1, b1, W2, b2, Wa, ba, Wtb, btb, seq);
        cfc_proj<<<dim3(2048), dim3(256), 0, stream>>>(
            seq, Wp1, bp1, Wp2, bp2, (float*)d_out);
    } else {
        cfc_fused_fb<<<dim3(16), dim3(512), 0, stream>>>(
            x, Wb, bb, W1, b1, W2, b2, Wa, ba, Wtb, btb, Wp1, bp1, Wp2, bp2,
            (float*)d_out);
    }
}